// Round 1
// 2455.938 us; speedup vs baseline: 1.0957x; 1.0957x over previous
//
#include <hip/hip_runtime.h>

// Problem constants
#define Bn 4
#define Nn 8192
#define Dn 64
#define Sn 2048
#define Kn 32
#define R2c 0.04f          // f32(0.2*0.2)
#define OUT_XYZ (Bn*Sn*3)  // 24576 floats of new_xyz, then feats

// Workspace layout (units = 4-byte elements)
#define WS_P4  0            // [B*N] float4 {x,y,z,0}
#define WS_WB1 131072       // bf16 W1' [64][96]  (feat-first permute, zero pad)
#define WS_WB2 134144       // bf16 W2  [128][64]
#define WS_WB3 138240       // bf16 W3  [256][128]
#define WS_GRP 154624       // int grp_idx [B*S][K]

#define HSTR 136            // bf16 LDS row stride (128 max C + 8 pad)

typedef __attribute__((ext_vector_type(8))) short short8;
typedef __attribute__((ext_vector_type(4))) float floatx4;
typedef __attribute__((ext_vector_type(2))) float float2v;

// float -> bf16 (RNE) without relying on header APIs
__device__ __forceinline__ unsigned short f2bf(float f) {
    unsigned u = __float_as_uint(f);
    return (unsigned short)((u + 0x7FFFu + ((u >> 16) & 1u)) >> 16);
}

// ---------------------------------------------------------------------------
// Prep: xyz -> float4 array; weights -> bf16 [O][Cp] row-major.
// ---------------------------------------------------------------------------
__global__ __launch_bounds__(256) void prep_kernel(const float* __restrict__ xyz,
                                                   const float* __restrict__ W1,
                                                   const float* __restrict__ W2,
                                                   const float* __restrict__ W3,
                                                   float* __restrict__ ws) {
    int id = blockIdx.x * 256 + threadIdx.x;
    if (id < Bn * Nn) {
        float4* p4 = (float4*)(ws + WS_P4);
        p4[id] = make_float4(xyz[id * 3 + 0], xyz[id * 3 + 1], xyz[id * 3 + 2], 0.f);
    }
    int i1 = id - Bn * Nn;
    if (i1 >= 0 && i1 < 64 * 96) {
        int o = i1 / 96, c = i1 % 96;
        float v = (c < 64) ? W1[o * 67 + 3 + c] : (c < 67 ? W1[o * 67 + (c - 64)] : 0.f);
        ((unsigned short*)(ws + WS_WB1))[i1] = f2bf(v);
    }
    int i2 = i1 - 64 * 96;
    if (i2 >= 0 && i2 < 128 * 64)
        ((unsigned short*)(ws + WS_WB2))[i2] = f2bf(W2[i2]);
    int i3 = i2 - 128 * 64;
    if (i3 >= 0 && i3 < 256 * 128)
        ((unsigned short*)(ws + WS_WB3))[i3] = f2bf(W3[i3]);
}

// DPP wave-64 max (VALU pipe); lane 63 holds full-wave max, broadcast via readlane.
__device__ __forceinline__ float wave_fmax_dpp(float x) {
    float t;
    t = __int_as_float(__builtin_amdgcn_update_dpp(0, __float_as_int(x), 0x111, 0xf, 0xf, true)); x = fmaxf(x, t);
    t = __int_as_float(__builtin_amdgcn_update_dpp(0, __float_as_int(x), 0x112, 0xf, 0xf, true)); x = fmaxf(x, t);
    t = __int_as_float(__builtin_amdgcn_update_dpp(0, __float_as_int(x), 0x114, 0xf, 0xf, true)); x = fmaxf(x, t);
    t = __int_as_float(__builtin_amdgcn_update_dpp(0, __float_as_int(x), 0x118, 0xf, 0xf, true)); x = fmaxf(x, t);
    t = __int_as_float(__builtin_amdgcn_update_dpp(0, __float_as_int(x), 0x142, 0xf, 0xf, true)); x = fmaxf(x, t);
    t = __int_as_float(__builtin_amdgcn_update_dpp(0, __float_as_int(x), 0x143, 0xf, 0xf, true)); x = fmaxf(x, t);
    return __int_as_float(__builtin_amdgcn_readlane(__float_as_int(x), 63));
}

// DPP wave-64 unsigned max (branchless index reduce). bound_ctrl injects 0,
// which is the identity for umax. Same ladder as wave_fmax_dpp.
__device__ __forceinline__ unsigned wave_umax_dpp(unsigned x) {
    unsigned t;
    t = (unsigned)__builtin_amdgcn_update_dpp(0, (int)x, 0x111, 0xf, 0xf, true); x = (t > x) ? t : x;
    t = (unsigned)__builtin_amdgcn_update_dpp(0, (int)x, 0x112, 0xf, 0xf, true); x = (t > x) ? t : x;
    t = (unsigned)__builtin_amdgcn_update_dpp(0, (int)x, 0x114, 0xf, 0xf, true); x = (t > x) ? t : x;
    t = (unsigned)__builtin_amdgcn_update_dpp(0, (int)x, 0x118, 0xf, 0xf, true); x = (t > x) ? t : x;
    t = (unsigned)__builtin_amdgcn_update_dpp(0, (int)x, 0x142, 0xf, 0xf, true); x = (t > x) ? t : x;
    t = (unsigned)__builtin_amdgcn_update_dpp(0, (int)x, 0x143, 0xf, 0xf, true); x = (t > x) ? t : x;
    return (unsigned)__builtin_amdgcn_readlane((int)x, 63);
}

// ---------------------------------------------------------------------------
// Farthest point sampling — packed-f32 rework of the R10 plateau config.
// 512 thr x 16 pts (as 8 point-PAIRS per thread), ONE barrier/step.
// Changes vs prior best (2417-2430 us):
//  * distance arithmetic via v_pk_{add,mul}_f32 (VOP3P): 2 points per
//    instruction, bit-exact per element (same IEEE ops in ref order:
//    pk_add(p,-c) == p-c; mul,mul,mul,add,add). Scalar f32 is half-rate on
//    gfx950; this halves the dominant per-step instruction stream.
//  * v_max3 fusion for the running lane max (fmaxf(fmaxf(lv,a),b)).
//  * branchless first-occurrence index reduce: umax-DPP ladder over
//    key = 0xFFFFFFFF - pb (replaces ballot/popc/readlane + divergent
//    shfl_xor slow path; identical tie semantics and key format).
//  * 3-level tree for the 8-key cross-wave max; readfirstlane'd winner
//    index so the uniform p4[p] fetch can take the scalar path.
// fmin/fmax stay scalar (no v_pk_min/max_f32 on gfx950).
// ---------------------------------------------------------------------------
__global__ __launch_bounds__(512, 2) void fps_kernel(const float* __restrict__ ws,
                                                     float* __restrict__ out_xyz) {
    #pragma clang fp contract(off)
    const int b = blockIdx.x;
    const int tid = threadIdx.x;
    const float4* p4 = (const float4*)(ws + WS_P4) + b * Nn;

    // pair u holds points j=2u (.x) and j=2u+1 (.y); global idx = j*512 + tid
    float2v pX[8], pY[8], pZ[8], dI[8];
    #pragma unroll
    for (int u = 0; u < 8; u++) {
        float4 va = p4[(2 * u) * 512 + tid];
        float4 vb = p4[(2 * u + 1) * 512 + tid];
        pX[u].x = va.x; pX[u].y = vb.x;
        pY[u].x = va.y; pY[u].y = vb.y;
        pZ[u].x = va.z; pZ[u].y = vb.z;
        dI[u].x = 1e10f; dI[u].y = 1e10f;
    }
    #pragma unroll
    for (int u = 0; u < 8; u++) {
        asm volatile("" : "+v"(pX[u]), "+v"(pY[u]), "+v"(pZ[u]), "+v"(dI[u]));
    }

    __shared__ unsigned long long sKey[2][8];
    __shared__ float sHist[Sn * 3];

    float4 c0 = p4[0];
    float cx = c0.x, cy = c0.y, cz = c0.z;

    for (int s = 0; s < Sn; s++) {
        const int par = s & 1;
        if (tid == 0) {
            sHist[s * 3 + 0] = cx;
            sHist[s * 3 + 1] = cy;
            sHist[s * 3 + 2] = cz;
        }
        // broadcast negated centroid into packed operands (p - c == p + (-c), exact)
        float nxs = -cx, nys = -cy, nzs = -cz;
        float2v nX, nY, nZ;
        nX.x = nxs; nX.y = nxs;
        nY.x = nys; nY.y = nys;
        nZ.x = nzs; nZ.y = nzs;

        float lv = -1.0f;
        #pragma unroll
        for (int u = 0; u < 8; u++) {
            float2v dx, dy, dz, xx, yy, zz, s1, d2;
            asm("v_pk_add_f32 %0, %1, %2" : "=v"(dx) : "v"(pX[u]), "v"(nX));
            asm("v_pk_add_f32 %0, %1, %2" : "=v"(dy) : "v"(pY[u]), "v"(nY));
            asm("v_pk_add_f32 %0, %1, %2" : "=v"(dz) : "v"(pZ[u]), "v"(nZ));
            asm("v_pk_mul_f32 %0, %1, %1" : "=v"(xx) : "v"(dx));
            asm("v_pk_mul_f32 %0, %1, %1" : "=v"(yy) : "v"(dy));
            asm("v_pk_mul_f32 %0, %1, %1" : "=v"(zz) : "v"(dz));
            asm("v_pk_add_f32 %0, %1, %2" : "=v"(s1) : "v"(xx), "v"(yy));
            asm("v_pk_add_f32 %0, %1, %2" : "=v"(d2) : "v"(s1), "v"(zz));
            float mx = fminf(dI[u].x, d2.x);
            float my = fminf(dI[u].y, d2.y);
            dI[u].x = mx; dI[u].y = my;
            lv = fmaxf(fmaxf(lv, mx), my);   // fuses to v_max3_f32
        }
        float wmax = wave_fmax_dpp(lv);

        // first-occurrence recovery: descending j so the last write wins
        int pb = 0x7fffffff;
        #pragma unroll
        for (int u = 7; u >= 0; u--) {
            if (dI[u].y == wmax) pb = (2 * u + 1) * 512 + tid;
            if (dI[u].x == wmax) pb = (2 * u) * 512 + tid;
        }
        // branchless wave-min of pb via umax on the complement
        unsigned best = wave_umax_dpp(0xFFFFFFFFu - (unsigned)pb);

        if ((tid & 63) == 0) {
            sKey[par][tid >> 6] =
                ((unsigned long long)__float_as_uint(wmax) << 32) |
                (unsigned long long)best;
        }
        __syncthreads();
        unsigned long long a0 = sKey[par][0], a1 = sKey[par][1];
        unsigned long long a2 = sKey[par][2], a3 = sKey[par][3];
        unsigned long long a4 = sKey[par][4], a5 = sKey[par][5];
        unsigned long long a6 = sKey[par][6], a7 = sKey[par][7];
        a0 = (a1 > a0) ? a1 : a0;
        a2 = (a3 > a2) ? a3 : a2;
        a4 = (a5 > a4) ? a5 : a4;
        a6 = (a7 > a6) ? a7 : a6;
        a0 = (a2 > a0) ? a2 : a0;
        a4 = (a6 > a4) ? a6 : a4;
        unsigned long long k = (a4 > a0) ? a4 : a0;

        int p = (int)(0xFFFFFFFFu - (unsigned)(k & 0xFFFFFFFFull));
        p = __builtin_amdgcn_readfirstlane(p);
        float4 c4 = p4[p];
        cx = c4.x; cy = c4.y; cz = c4.z;
    }

    __syncthreads();
    float4* o4 = (float4*)(out_xyz + b * Sn * 3);
    const float4* h4 = (const float4*)sHist;
    #pragma unroll
    for (int i = tid; i < Sn * 3 / 4; i += 512) o4[i] = h4[i];
}

// ---------------------------------------------------------------------------
// Ball query (unchanged; exact-decision verified: absmax 0.0).
// ---------------------------------------------------------------------------
__global__ __launch_bounds__(256) void ballq_kernel(const float* __restrict__ ws,
                                                    const float* __restrict__ newxyz,
                                                    int* __restrict__ grp) {
    #pragma clang fp contract(off)
    int t = blockIdx.x * 256 + threadIdx.x;
    int wid = t >> 6;
    int lane = t & 63;
    int b = wid >> 11;
    const float4* p4 = (const float4*)(ws + WS_P4) + b * Nn;

    float nx = newxyz[wid * 3 + 0], ny = newxyz[wid * 3 + 1], nz = newxyz[wid * 3 + 2];
    float a2 = (nx * nx + ny * ny) + nz * nz;

    int total = 0;
    int firstp = 0;
    for (int c = 0; c < Nn / 64; c++) {
        int p = c * 64 + lane;
        float4 v = p4[p];
        float x = v.x, y = v.y, z = v.z;
        float bv = (x * x + y * y) + z * z;
        float dot = __builtin_fmaf(nx, x, 0.0f);
        dot = __builtin_fmaf(ny, y, dot);
        dot = __builtin_fmaf(nz, z, dot);
        float sq = (a2 + bv) - 2.0f * dot;
        bool hit = !(sq > R2c);
        unsigned long long mask = __ballot(hit);
        if (mask) {
            if (total == 0) firstp = c * 64 + (__ffsll(mask) - 1);
            int rank = __popcll(mask & ((1ull << lane) - 1ull));
            int slot = total + rank;
            if (hit && slot < Kn) grp[wid * Kn + slot] = p;
            total += (int)__popcll(mask);
            if (total >= Kn) break;
        }
    }
    if (lane >= total && lane < Kn) grp[wid * Kn + lane] = firstp;
}

// ---------------------------------------------------------------------------
// MFMA MLP (unchanged): one group per block, 256 threads = 4 waves.
// ---------------------------------------------------------------------------
template<int KB, int O>
__device__ __forceinline__ void mfma_layer(const unsigned short* __restrict__ X,
                                           unsigned short* __restrict__ Y,
                                           const unsigned short* __restrict__ wb,
                                           const float* __restrict__ bias,
                                           int lane, int wv) {
    const int Cp = KB * 32;
    const int mt = wv & 1;
    const int mrow = mt * 16 + (lane & 15);
    const int quad = lane >> 4;

    short8 a[KB];
    #pragma unroll
    for (int kb = 0; kb < KB; kb++)
        a[kb] = *(const short8*)&X[mrow * HSTR + kb * 32 + quad * 8];

    for (int nt = (wv >> 1); nt < O / 16; nt += 2) {
        int n0 = nt * 16;
        float bv = bias[n0 + (lane & 15)];
        floatx4 acc = {bv, bv, bv, bv};
        #pragma unroll
        for (int kb = 0; kb < KB; kb++) {
            short8 bf = *(const short8*)&wb[(n0 + (lane & 15)) * Cp + kb * 32 + quad * 8];
            acc = __builtin_amdgcn_mfma_f32_16x16x32_bf16(a[kb], bf, acc, 0, 0, 0);
        }
        #pragma unroll
        for (int r = 0; r < 4; r++) {
            float v = fmaxf(acc[r], 0.f);
            int m = mt * 16 + quad * 4 + r;
            Y[m * HSTR + n0 + (lane & 15)] = f2bf(v);
        }
    }
}

__global__ __launch_bounds__(256) void mlp_kernel(const float* __restrict__ xyz,
                                                  const float* __restrict__ feat,
                                                  const float* __restrict__ ws,
                                                  const int* __restrict__ grp,
                                                  const float* __restrict__ b1,
                                                  const float* __restrict__ b2,
                                                  const float* __restrict__ b3,
                                                  float* __restrict__ out) {
    __shared__ __align__(16) unsigned short hA[32 * HSTR];
    __shared__ __align__(16) unsigned short hB[32 * HSTR];
    __shared__ float mxs[2][256];
    __shared__ int   sIdx[Kn];
    __shared__ float sCent[3];

    int g = blockIdx.x;            // b*S + s
    int b = g >> 11;
    int tid = threadIdx.x;
    int lane = tid & 63, wv = tid >> 6;

    if (tid < Kn) sIdx[tid] = grp[g * Kn + tid];
    if (tid == 0) { sCent[0] = out[g*3]; sCent[1] = out[g*3+1]; sCent[2] = out[g*3+2]; }
    // zero hA (pad cols must be 0 for the K=96 layer)
    {
        short8 z = {0,0,0,0,0,0,0,0};
        for (int i = tid; i < 32 * HSTR / 8; i += 256)
            ((short8*)hA)[i] = z;
    }
    __syncthreads();

    { // stage h0: feats -> cols 0..63 (bf16x8 vector writes), xyz -> 64..66
        int m = tid >> 3, m8 = tid & 7;
        int idx = sIdx[m];
        int base = b * Nn + idx;
        const float4* f4 = (const float4*)(feat + base * 64 + m8 * 8);
        float4 va = f4[0], vb = f4[1];
        short8 pk;
        pk[0] = (short)f2bf(va.x); pk[1] = (short)f2bf(va.y);
        pk[2] = (short)f2bf(va.z); pk[3] = (short)f2bf(va.w);
        pk[4] = (short)f2bf(vb.x); pk[5] = (short)f2bf(vb.y);
        pk[6] = (short)f2bf(vb.z); pk[7] = (short)f2bf(vb.w);
        *(short8*)&hA[m * HSTR + m8 * 8] = pk;
        if (m8 == 0) {
            hA[m * HSTR + 64] = f2bf(xyz[base * 3 + 0] - sCent[0]);
            hA[m * HSTR + 65] = f2bf(xyz[base * 3 + 1] - sCent[1]);
            hA[m * HSTR + 66] = f2bf(xyz[base * 3 + 2] - sCent[2]);
        }
    }
    __syncthreads();

    const unsigned short* wb1 = (const unsigned short*)(ws + WS_WB1);
    const unsigned short* wb2 = (const unsigned short*)(ws + WS_WB2);
    const unsigned short* wb3 = (const unsigned short*)(ws + WS_WB3);

    mfma_layer<3, 64>(hA, hB, wb1, b1, lane, wv);     // 96 -> 64
    __syncthreads();
    mfma_layer<2, 128>(hB, hA, wb2, b2, lane, wv);    // 64 -> 128
    __syncthreads();

    { // L3 (128 -> 256) + fused maxpool
        const int mt = wv & 1;
        const int mrow = mt * 16 + (lane & 15);
        const int quad = lane >> 4;
        short8 a[4];
        #pragma unroll
        for (int kb = 0; kb < 4; kb++)
            a[kb] = *(const short8*)&hA[mrow * HSTR + kb * 32 + quad * 8];
        for (int nt = (wv >> 1); nt < 16; nt += 2) {
            int n0 = nt * 16;
            float bv = b3[n0 + (lane & 15)];
            floatx4 acc = {bv, bv, bv, bv};
            #pragma unroll
            for (int kb = 0; kb < 4; kb++) {
                short8 bf = *(const short8*)&wb3[(n0 + (lane & 15)) * 128 + kb * 32 + quad * 8];
                acc = __builtin_amdgcn_mfma_f32_16x16x32_bf16(a[kb], bf, acc, 0, 0, 0);
            }
            float pm = fmaxf(fmaxf(fmaxf(acc[0], acc[1]), fmaxf(acc[2], acc[3])), 0.f);
            pm = fmaxf(pm, __shfl_xor(pm, 16));   // reduce across the 4 quads
            pm = fmaxf(pm, __shfl_xor(pm, 32));
            if (lane < 16) mxs[mt][n0 + lane] = pm;
        }
    }
    __syncthreads();

    out[OUT_XYZ + g * 256 + tid] = fmaxf(mxs[0][tid], mxs[1][tid]);
}

// ---------------------------------------------------------------------------
extern "C" void kernel_launch(void* const* d_in, const int* in_sizes, int n_in,
                              void* d_out, int out_size, void* d_ws, size_t ws_size,
                              hipStream_t stream) {
    const float* xyz  = (const float*)d_in[0];
    const float* feat = (const float*)d_in[1];
    const float* W1   = (const float*)d_in[2];
    const float* b1   = (const float*)d_in[3];
    const float* W2   = (const float*)d_in[4];
    const float* b2   = (const float*)d_in[5];
    const float* W3   = (const float*)d_in[6];
    const float* b3   = (const float*)d_in[7];
    float* out = (float*)d_out;
    float* ws  = (float*)d_ws;
    int*   grp = (int*)d_ws + WS_GRP;

    hipLaunchKernelGGL(prep_kernel, dim3(312), dim3(256), 0, stream, xyz, W1, W2, W3, ws);
    hipLaunchKernelGGL(fps_kernel, dim3(Bn), dim3(512), 0, stream, ws, out);
    hipLaunchKernelGGL(ballq_kernel, dim3(Bn * Sn / 4), dim3(256), 0, stream, ws, out, grp);
    hipLaunchKernelGGL(mlp_kernel, dim3(Bn * Sn), dim3(256), 0, stream,
                       xyz, feat, ws, grp, b1, b2, b3, out);
}